// Round 12
// baseline (390.465 us; speedup 1.0000x reference)
//
#include <hip/hip_runtime.h>
#include <stdint.h>

#define Bn 32
#define Nn 1723
#define Cn 512
#define Hn 256
#define MTA 54    // ceil(1723/32): stage-A tiles == supT 32-k sub-steps
#define MTB 27    // stage-B row tiles (64 rows each)

typedef __bf16 bf16x8 __attribute__((ext_vector_type(8)));
typedef float f32x4 __attribute__((ext_vector_type(4)));
typedef unsigned short u16;

__device__ __forceinline__ u16 f2b(float f){
  union{float f; uint32_t i;} c; c.f=f; uint32_t u=c.i;
  u += 0x7fffu + ((u>>16)&1u);
  return (u16)(u>>16);
}
__device__ __forceinline__ bf16x8 ld8(const u16* p){
  union{ uint4 u; bf16x8 b; } c;
  c.u = *reinterpret_cast<const uint4*>(p);
  return c.b;
}
__device__ __forceinline__ f32x4 mfma16(bf16x8 a, bf16x8 b, f32x4 c){
  return __builtin_amdgcn_mfma_f32_16x16x32_bf16(a,b,c,0,0,0);
}
__device__ __forceinline__ bf16x8 cvt8(float4 a, float4 b){
  union{ uint32_t w[4]; bf16x8 v; } r;
  asm("v_cvt_pk_bf16_f32 %0, %1, %2" : "=v"(r.w[0]) : "v"(a.x), "v"(a.y));
  asm("v_cvt_pk_bf16_f32 %0, %1, %2" : "=v"(r.w[1]) : "v"(a.z), "v"(a.w));
  asm("v_cvt_pk_bf16_f32 %0, %1, %2" : "=v"(r.w[2]) : "v"(b.x), "v"(b.y));
  asm("v_cvt_pk_bf16_f32 %0, %1, %2" : "=v"(r.w[3]) : "v"(b.z), "v"(b.w));
  return r.v;
}
#define VMW(n)  asm volatile("s_waitcnt vmcnt(" #n ")" ::: "memory")
#define CFENCE() asm volatile("" ::: "memory")
// default cache policy (sup: keep in L2)
#define GLD_LDS16(gp, lp) \
  __builtin_amdgcn_global_load_lds((const __attribute__((address_space(1))) void*)(gp), \
                                   (__attribute__((address_space(3))) void*)(lp), 16, 0, 0)
// NT / streaming policy (adj: don't evict sup from L2)
#define GLD_LDS16NT(gp, lp) \
  __builtin_amdgcn_global_load_lds((const __attribute__((address_space(1))) void*)(gp), \
                                   (__attribute__((address_space(3))) void*)(lp), 16, 0, 2)

// ---- kernel 0: weights -> bf16 MFMA-fragment-major (validated R5) ----
__global__ __launch_bounds__(256) void k_prep(
    const float* __restrict__ W1, const float* __restrict__ Wc, const float* __restrict__ W2,
    u16* __restrict__ W1f, u16* __restrict__ WcTf, u16* __restrict__ W2f)
{
  const int t = blockIdx.x*256 + threadIdx.x;
  const int lane = t & 63, unit = t >> 6;
  const int lr = lane & 15, lh = lane >> 4;
  const float* src; u16* dst; int K, tile, kk; bool tr = false;
  if (unit < 256){ tile = unit>>4; kk = unit&15; src = W1; dst = W1f; K = 512; }
  else if (unit < 384){ int u = unit-256; tile = u>>3; kk = u&7; src = Wc; dst = WcTf; K = 256; tr = true; }
  else { int u = unit-384; tile = u>>3; kk = u&7; src = W2; dst = W2f; K = 256; }
  const int row = tile*16 + lr;
  const int k0 = kk*32 + lh*8;
  union{u16 s[8]; uint4 u;} o;
  #pragma unroll
  for (int j=0;j<8;++j){
    float v = tr ? src[(size_t)(k0+j)*256 + row] : src[(size_t)row*K + k0 + j];
    o.s[j] = f2b(v);
  }
  *reinterpret_cast<uint4*>(dst + (size_t)(tile*(K/32)+kk)*512 + lane*8) = o.u;
}

// ---------------- stage A (validated; phantom vertices ZEROED in supT) ----------------
__global__ __launch_bounds__(256) void k_stageA(
    const float* __restrict__ x, const float* __restrict__ prw, const float* __restrict__ prb,
    const u16* __restrict__ W1f, const float* __restrict__ b1,
    const float* __restrict__ n1w, const float* __restrict__ n1b,
    const u16* __restrict__ WcTf, u16* __restrict__ supT)
{
  __shared__ u16 t1[32*512];
  __shared__ float ps[2][32], pq[2][32];
  u16* const t2 = t1;
  const int b = blockIdx.y;
  const int m0 = blockIdx.x*32;
  const int tid = threadIdx.x;
  const int w = tid>>6, l = tid&63, lr = l&15, lh = l>>4;
  const int wm = w>>1, wn = w&1;

  float pw[8], pb[8];
  #pragma unroll
  for (int j=0;j<8;++j){ pw[j]=prw[l*8+j]; pb[j]=prb[l*8+j]; }
  #pragma unroll
  for (int rr=0; rr<8; ++rr){
    const int rloc = w*8+rr;
    int rg = m0 + rloc; rg = rg < Nn ? rg : Nn-1;
    const float* src = x + ((size_t)b*Nn + rg)*Cn + l*8;
    float4 c0 = *reinterpret_cast<const float4*>(src);
    float4 c1 = *reinterpret_cast<const float4*>(src+4);
    float v[8] = {c0.x,c0.y,c0.z,c0.w,c1.x,c1.y,c1.z,c1.w};
    float s=0.f, q=0.f;
    #pragma unroll
    for (int j=0;j<8;++j){ s+=v[j]; q+=v[j]*v[j]; }
    #pragma unroll
    for (int m=1;m<64;m<<=1){ s += __shfl_xor(s,m); q += __shfl_xor(q,m); }
    const float mean = s*(1.f/Cn);
    const float rstd = rsqrtf(fmaxf(q*(1.f/Cn) - mean*mean, 0.f) + 1e-12f);
    union{uint4 u; u16 s[8];} ov;
    #pragma unroll
    for (int j=0;j<8;++j){
      float t = (v[j]-mean)*rstd*pw[j] + pb[j];
      ov.s[j] = f2b(fmaxf(t,0.f));
    }
    const int idx = (rloc*512 + l*8) ^ ((rloc&7)<<3);
    *reinterpret_cast<uint4*>(&t1[idx]) = ov.u;
  }
  __syncthreads();

  f32x4 acc[8];
  #pragma unroll
  for (int i=0;i<8;++i) acc[i] = f32x4{0.f,0.f,0.f,0.f};
  const int arow = wm*16 + lr;
  const int aswz = (arow&7)<<3;
  for (int kk=0; kk<16; ++kk){
    bf16x8 a = ld8(&t1[(arow*512 + kk*32 + lh*8) ^ aswz]);
    #pragma unroll
    for (int nt=0; nt<8; ++nt){
      bf16x8 bb = ld8(W1f + (size_t)(((wn*8+nt)*16 + kk))*512 + l*8);
      acc[nt] = mfma16(a, bb, acc[nt]);
    }
  }

  float sum[4]={0,0,0,0}, sq[4]={0,0,0,0};
  #pragma unroll
  for (int nt=0; nt<8; ++nt){
    const float bias = b1[wn*128+nt*16+lr];
    #pragma unroll
    for (int r=0;r<4;++r){
      float vv = acc[nt][r] + bias;
      acc[nt][r] = vv; sum[r]+=vv; sq[r]+=vv*vv;
    }
  }
  #pragma unroll
  for (int m=1;m<16;m<<=1){
    #pragma unroll
    for (int r=0;r<4;++r){ sum[r]+=__shfl_xor(sum[r],m); sq[r]+=__shfl_xor(sq[r],m); }
  }
  if (lr==0){
    #pragma unroll
    for (int r=0;r<4;++r){
      const int row = wm*16 + lh*4 + r;
      ps[wn][row]=sum[r]; pq[wn][row]=sq[r];
    }
  }
  __syncthreads();
  float mean[4], rstd[4];
  #pragma unroll
  for (int r=0;r<4;++r){
    const int row = wm*16 + lh*4 + r;
    const float S = ps[0][row]+ps[1][row];
    const float Q = pq[0][row]+pq[1][row];
    const float mu = S*(1.f/Hn);
    mean[r] = mu;
    rstd[r] = rsqrtf(fmaxf(Q*(1.f/Hn) - mu*mu, 0.f) + 1e-12f);
  }
  #pragma unroll
  for (int nt=0; nt<8; ++nt){
    const int col = wn*128+nt*16+lr;
    const float nw = n1w[col], nb = n1b[col];
    #pragma unroll
    for (int r=0;r<4;++r){
      const int row = wm*16 + lh*4 + r;
      float t = (acc[nt][r]-mean[r])*rstd[r]*nw + nb;
      t2[(row*256 + col) ^ ((row&7)<<3)] = f2b(fmaxf(t,0.f));
    }
  }
  __syncthreads();

  f32x4 acc2[8];
  #pragma unroll
  for (int i=0;i<8;++i) acc2[i] = f32x4{0.f,0.f,0.f,0.f};
  for (int kk=0; kk<8; ++kk){
    bf16x8 a = ld8(&t2[(arow*256 + kk*32 + lh*8) ^ aswz]);
    #pragma unroll
    for (int nt=0; nt<8; ++nt){
      bf16x8 bb = ld8(WcTf + (size_t)(((wn*8+nt)*8 + kk))*512 + l*8);
      acc2[nt] = mfma16(a, bb, acc2[nt]);
    }
  }

  const int off512 = (wm*2 + (lh>>1))*128 + lr*8 + (lh&1)*4;
  const int vbase = m0 + wm*16 + lh*4;
  #pragma unroll
  for (int nt=0; nt<8; ++nt){
    const int htile = wn*8 + nt;
    const size_t base = ((size_t)(b*16 + htile)*MTA + blockIdx.x)*512 + off512;
    ushort4 o;
    o.x = (vbase+0 < Nn) ? f2b(acc2[nt][0]) : (u16)0;
    o.y = (vbase+1 < Nn) ? f2b(acc2[nt][1]) : (u16)0;
    o.z = (vbase+2 < Nn) ? f2b(acc2[nt][2]) : (u16)0;
    o.w = (vbase+3 < Nn) ? f2b(acc2[nt][3]) : (u16)0;
    *reinterpret_cast<ushort4*>(supT + base) = o;
  }
}

// ---------------- stage B: M=64, all-gll, LDS-shared sup, counted FIFO ----------------
// grid 864 = 8 XCD x (4 b x 27 tiles of 64 rows). 4 waves as 2x2 (wm,wn).
// adj: NT glls, 4-buf (lead 2-3 steps). sup: default glls into shared LDS, 2-buf (lead 1).
// Per step per wave: 4 sup glls + 2 adj glls; top wait VMW(2); no reg VMEM in K-loop.
__global__ __launch_bounds__(256) void k_stageB(
    const float* __restrict__ adj, const u16* __restrict__ supT,
    const float* __restrict__ cb, const float* __restrict__ n2w, const float* __restrict__ n2b,
    const u16* __restrict__ W2f, const float* __restrict__ bl2,
    const float* __restrict__ x, float* __restrict__ out)
{
  __shared__ float abuf[4][64*32];   // 32 KB: adj ring, 4-float-block XOR(row&7) swizzle
  __shared__ u16  sbuf[2][16*512];   // 32 KB: sup dbuf, fragment-major (linear)
  __shared__ float ps[2][64], pq[2][64];
  u16* const t3 = (u16*)&abuf[0][0]; // 32 KB alias after K-loop
  const int bid = blockIdx.x;
  const int xcd = bid & 7, idx = bid >> 3;
  const int b = xcd*4 + (idx & 3);          // 4 consecutive b per XCD
  const int m0 = (idx >> 2) * 64;
  const int tid = threadIdx.x, w = tid>>6, l = tid&63, lr = l&15, lh = l>>4;
  const int wm = w>>1, wn = w&1;

  const float* adjb = adj + (size_t)b*Nn*Nn;
  const u16* supb = supT + (size_t)b*16*MTA*512;

  // adj gll geometry: gll g covers local rows 16w+8g..+7; lane: row=(l>>3), chunk=l&7
  // source 4-float block pre-swizzled: (chunk ^ (row&7))
  const float *gA0, *gA1;
  {
    int rl0 = 16*w + (l>>3);       int rg0 = m0+rl0 < Nn ? m0+rl0 : Nn-1;
    int rl1 = 16*w + 8 + (l>>3);   int rg1 = m0+rl1 < Nn ? m0+rl1 : Nn-1;
    gA0 = adjb + (size_t)rg0*Nn + (((l&7) ^ (rl0&7))<<2);
    gA1 = adjb + (size_t)rg1*Nn + (((l&7) ^ (rl1&7))<<2);
  }

  f32x4 acc1[2][8];
  #pragma unroll
  for (int i=0;i<2;++i)
    #pragma unroll
    for (int j=0;j<8;++j) acc1[i][j] = f32x4{0.f,0.f,0.f,0.f};

  #define AISSUE(buf, s) do{                                             \
    GLD_LDS16NT(gA0 + (size_t)(s)*32, &abuf[buf][(16*w)*32]);            \
    GLD_LDS16NT(gA1 + (size_t)(s)*32, &abuf[buf][(16*w+8)*32]);          \
  }while(0)

  #define SISSUE(buf, s) do{                                             \
    _Pragma("unroll")                                                    \
    for (int j=0;j<4;++j)                                                \
      GLD_LDS16(supb + (size_t)((4*w+j)*MTA + (s))*512 + l*8,            \
                &sbuf[buf][(4*w+j)*512]);                                \
  }while(0)

  #define MSTEP(bufA, bufS) do{                                          \
    bf16x8 bbv[8];                                                       \
    _Pragma("unroll")                                                    \
    for (int nt=0;nt<8;++nt)                                             \
      bbv[nt] = ld8(&sbuf[bufS][(wn*8+nt)*512 + l*8]);                   \
    _Pragma("unroll")                                                    \
    for (int mt=0;mt<2;++mt){                                            \
      const int row = wm*32 + mt*16 + lr;                                \
      const int o0 = row*32 + (((lh*2) ^ (row&7))<<2);                   \
      float4 v0 = *reinterpret_cast<const float4*>(&abuf[bufA][0] + o0); \
      float4 v1 = *reinterpret_cast<const float4*>(&abuf[bufA][0] + (o0^4)); \
      bf16x8 af = cvt8(v0, v1);                                          \
      _Pragma("unroll")                                                  \
      for (int nt=0;nt<8;++nt) acc1[mt][nt] = mfma16(af, bbv[nt], acc1[mt][nt]); \
    }                                                                    \
  }while(0)

  // ---- prologue: FIFO = [A(0)2, A(1)2, S(0)4, A(2)2] ----
  AISSUE(0, 0); AISSUE(1, 1); CFENCE();
  SISSUE(0, 0); CFENCE();
  AISSUE(2, 2); CFENCE();

  // ---- main loop s=0..50: VMW(2) keeps A(s+2); issue S(s+1) then A(s+3) ----
  #pragma unroll 1
  for (int s=0; s<=50; ++s){
    VMW(2); __builtin_amdgcn_s_barrier(); CFENCE();
    SISSUE((s+1)&1, s+1); CFENCE();
    if (s <= 49) { AISSUE((s+3)&3, s+3); CFENCE(); }
    MSTEP(s&3, s&1);
  }
  // ---- peel s=51: queue [A(52)2, S(51)4] -> drain all ----
  VMW(0); __builtin_amdgcn_s_barrier(); CFENCE();
  SISSUE(0, 52); CFENCE();
  MSTEP(3, 1);
  // ---- peel s=52: + reg-stage A(53) (k 1696..1727, guarded) into abuf[1] ----
  VMW(0); __builtin_amdgcn_s_barrier(); CFENCE();
  SISSUE(1, 53); CFENCE();
  float tv[8];
  {
    const int trow = tid & 63, p = tid >> 6;
    int rg = m0 + trow; rg = rg < Nn ? rg : Nn-1;
    const float* rp = adjb + (size_t)rg*Nn;
    #pragma unroll
    for (int j=0;j<8;++j){
      const int k = 1696 + p*8 + j;
      tv[j] = (k < Nn) ? rp[k] : 0.f;
    }
  }
  CFENCE();
  MSTEP(0, 0);
  VMW(0);                          // reg loads + S(53) landed
  {
    const int trow = tid & 63, p = tid >> 6;
    const int a0 = trow*32 + (((2*p)   ^ (trow&7))<<2);
    const int a1 = trow*32 + (((2*p+1) ^ (trow&7))<<2);
    *reinterpret_cast<float4*>(&abuf[1][0] + a0) = float4{tv[0],tv[1],tv[2],tv[3]};
    *reinterpret_cast<float4*>(&abuf[1][0] + a1) = float4{tv[4],tv[5],tv[6],tv[7]};
  }
  __syncthreads();
  // ---- peel s=53 ----
  MSTEP(1, 1);
  __syncthreads();                 // K-loop over; abuf lifetime ends (t3 alias safe)

  // ---- +conv_b, LN(256) across wn pairs, relu -> t3 ----
  float sum[2][4], sq[2][4];
  #pragma unroll
  for (int mt=0;mt<2;++mt)
    #pragma unroll
    for (int r=0;r<4;++r){ sum[mt][r]=0.f; sq[mt][r]=0.f; }
  #pragma unroll
  for (int nt=0;nt<8;++nt){
    const float bias = cb[wn*128+nt*16+lr];
    #pragma unroll
    for (int mt=0;mt<2;++mt)
      #pragma unroll
      for (int r=0;r<4;++r){
        float vv = acc1[mt][nt][r] + bias;
        acc1[mt][nt][r] = vv; sum[mt][r]+=vv; sq[mt][r]+=vv*vv;
      }
  }
  #pragma unroll
  for (int m=1;m<16;m<<=1){
    #pragma unroll
    for (int mt=0;mt<2;++mt)
      #pragma unroll
      for (int r=0;r<4;++r){ sum[mt][r]+=__shfl_xor(sum[mt][r],m); sq[mt][r]+=__shfl_xor(sq[mt][r],m); }
  }
  if (lr==0){
    #pragma unroll
    for (int mt=0;mt<2;++mt)
      #pragma unroll
      for (int r=0;r<4;++r){
        const int row = wm*32 + mt*16 + lh*4 + r;
        ps[wn][row]=sum[mt][r]; pq[wn][row]=sq[mt][r];
      }
  }
  __syncthreads();
  float meanv[2][4], rstdv[2][4];
  #pragma unroll
  for (int mt=0;mt<2;++mt)
    #pragma unroll
    for (int r=0;r<4;++r){
      const int row = wm*32 + mt*16 + lh*4 + r;
      const float S = ps[0][row]+ps[1][row];
      const float Q = pq[0][row]+pq[1][row];
      const float mu = S*(1.f/Hn);
      meanv[mt][r] = mu;
      rstdv[mt][r] = rsqrtf(fmaxf(Q*(1.f/Hn)-mu*mu, 0.f) + 1e-12f);
    }
  #pragma unroll
  for (int nt=0;nt<8;++nt){
    const int c2 = wn*128+nt*16+lr;
    const float nw = n2w[c2], nb = n2b[c2];
    #pragma unroll
    for (int mt=0;mt<2;++mt)
      #pragma unroll
      for (int r=0;r<4;++r){
        const int row = wm*32 + mt*16 + lh*4 + r;
        float t = (acc1[mt][nt][r]-meanv[mt][r])*rstdv[mt][r]*nw + nb;
        t3[(row*256+c2) ^ ((row&7)<<3)] = f2b(fmaxf(t,0.f));
      }
  }
  __syncthreads();

  // ---- GEMM2 (two 64-col halves): y[64x512] = t3 @ lin2_W^T (K=256) ----
  #pragma unroll
  for (int h=0; h<2; ++h){
    f32x4 acc2[4][4];
    #pragma unroll
    for (int i=0;i<4;++i)
      #pragma unroll
      for (int j=0;j<4;++j) acc2[i][j] = f32x4{0.f,0.f,0.f,0.f};
    for (int kk=0;kk<8;++kk){
      bf16x8 a[4];
      #pragma unroll
      for (int mt=0;mt<4;++mt){
        const int row = mt*16+lr;
        a[mt] = ld8(&t3[(row*256 + kk*32 + lh*8) ^ ((row&7)<<3)]);
      }
      #pragma unroll
      for (int nt=0;nt<4;++nt){
        bf16x8 bb = ld8(W2f + (size_t)(((w*8 + h*4 + nt)*8) + kk)*512 + l*8);
        #pragma unroll
        for (int mt=0;mt<4;++mt) acc2[mt][nt] = mfma16(a[mt], bb, acc2[mt][nt]);
      }
    }
    #pragma unroll
    for (int nt=0;nt<4;++nt){
      const int c2 = w*128 + h*64 + nt*16 + lr;
      const float bias = bl2[c2];
      #pragma unroll
      for (int mt=0;mt<4;++mt){
        #pragma unroll
        for (int r=0;r<4;++r){
          const int mg = m0 + mt*16 + lh*4 + r;
          if (mg < Nn){
            const size_t off = ((size_t)b*Nn + mg)*Cn + c2;
            out[off] = acc2[mt][nt][r] + bias + x[off];
          }
        }
      }
    }
  }
  #undef AISSUE
  #undef SISSUE
  #undef MSTEP
}

extern "C" void kernel_launch(void* const* d_in, const int* in_sizes, int n_in,
                              void* d_out, int out_size, void* d_ws, size_t ws_size,
                              hipStream_t stream){
  const float* x    = (const float*)d_in[0];
  const float* adj  = (const float*)d_in[1];
  const float* prw  = (const float*)d_in[2];
  const float* prb  = (const float*)d_in[3];
  const float* W1   = (const float*)d_in[4];
  const float* b1   = (const float*)d_in[5];
  const float* n1w  = (const float*)d_in[6];
  const float* n1b  = (const float*)d_in[7];
  const float* Wc   = (const float*)d_in[8];
  const float* cbv  = (const float*)d_in[9];
  const float* n2w  = (const float*)d_in[10];
  const float* n2b  = (const float*)d_in[11];
  const float* W2   = (const float*)d_in[12];
  const float* bl2  = (const float*)d_in[13];

  u16* ws    = (u16*)d_ws;
  u16* W1f   = ws;                           // 131072 u16
  u16* WcTf  = ws + 131072;                  // 65536
  u16* W2f   = ws + 131072 + 65536;          // 131072
  u16* supT  = ws + 131072 + 65536 + 131072; // 32*16*54*512 u16 (~28.3 MB)

  k_prep<<<dim3(160), dim3(256), 0, stream>>>(W1, Wc, W2, W1f, WcTf, W2f);
  k_stageA<<<dim3(MTA,Bn), dim3(256), 0, stream>>>(x, prw, prb, W1f, b1, n1w, n1b, WcTf, supT);
  k_stageB<<<dim3(MTB*Bn), dim3(256), 0, stream>>>(adj, supT, cbv, n2w, n2b, W2f, bl2, x, (float*)d_out);
}